// Round 4
// baseline (1784.522 us; speedup 1.0000x reference)
//
#include <hip/hip_runtime.h>
#include <cstdint>
#include <cstddef>

// LaminarV1V2Network: B=1024, T=512, N=36, H=128, D_in=74, K=202.
// R8: software-pipelined GEMMs across phases (acc carried in regs):
//   P1(t): zr finish slabs 0-1 (w0-7, 4 MFMA) + epilogue || h start slabs 0-1
//          (w8-15, 2 MFMA) || l23dot (w13-15) || l4-finalize+stim (w8-12 hi-lanes)
//   P3(t): h finish slabs 2-6 (w8-15, 5 MFMA) + h epilogue || l4part-dot (w0-2)
//          || somdot (w3-5) || PV (w6) || cue(t+1)->xa (w7)
//   P5(t): zr(t+1) partial slabs 2-6 (w0-7, 10 MFMA, acc kept) || heads (w8-10)
//          || cue(t+1)->xb (w11)
//   P6(t): softmax + pointwise + l23 write (w0-3)
// Ring weights stored chunk-major [9][36]xfloat4 -> conflict-free dot reads.
// HSTR 136->144: disjoint bank windows for the two q-half b16 writes.
// 256 blocks x 1024 threads (16 waves), RPB=4, 4 lgkm-only barriers/step.

#define NN   36
#define HH   128
#define DIN  74
#define KT   202
#define KP   232      // row = 116 words == 20 mod 32 -> 8-row map bank-uniform
#define TT   512
#define RPB  4
#define NPAD 40
#define HSTR 144      // hb row stride (shorts): 72 words == 8 mod 32
#define S2   6        // second-dim stride for hS/zgS/preq

typedef short bf16x8 __attribute__((ext_vector_type(8)));
typedef float f32x4  __attribute__((ext_vector_type(4)));

#define MFMA(a,b,c) __builtin_amdgcn_mfma_f32_16x16x32_bf16((a),(b),(c),0,0,0)
// Barrier that orders LDS only: global loads/stores float across it.
#define BAR() asm volatile("s_waitcnt lgkmcnt(0)\n\ts_barrier" ::: "memory")

__device__ __forceinline__ float fastrcp(float x) { return __builtin_amdgcn_rcpf(x); }
__device__ __forceinline__ float sigmf(float x) { return fastrcp(1.0f + __expf(-x)); }
__device__ __forceinline__ float tanhf_fast(float x) {
    return 1.0f - 2.0f * fastrcp(1.0f + __expf(2.0f * x));
}

__device__ __forceinline__ short f2bf(float v) {
    union { float f; unsigned u; } x; x.f = v;
    unsigned r = (x.u + 0x7fffu + ((x.u >> 16) & 1u)) >> 16;   // RNE
    return (short)r;
}
__device__ __forceinline__ float bf2f(short s) {
    union { unsigned u; float f; } y; y.u = ((unsigned)(unsigned short)s) << 16;
    return y.f;
}

// v_cvt_pk_bf16_f32: dst[15:0]=bf16(a), dst[31:16]=bf16(b), RNE (same as f2bf).
__device__ __forceinline__ unsigned cvtpk(float a, float b) {
    unsigned r;
    asm("v_cvt_pk_bf16_f32 %0, %1, %2" : "=v"(r) : "v"(a), "v"(b));
    return r;
}
__device__ __forceinline__ float lo16f(unsigned p) { return __uint_as_float(p << 16); }
__device__ __forceinline__ float hi16f(unsigned p) { return __uint_as_float(p & 0xffff0000u); }

// 16-lane butterfly reduction at VALU speed via DPP.
#define DPP_STEP_MAX(x, ctrl) \
    x = fmaxf(x, __int_as_float(__builtin_amdgcn_update_dpp(0, __float_as_int(x), (ctrl), 0xF, 0xF, true)))
#define DPP_STEP_SUM(x, ctrl) \
    x = x + __int_as_float(__builtin_amdgcn_update_dpp(0, __float_as_int(x), (ctrl), 0xF, 0xF, true))

__device__ __forceinline__ float red16_max(float x) {
    DPP_STEP_MAX(x, 0xB1);   // quad_perm xor1
    DPP_STEP_MAX(x, 0x4E);   // quad_perm xor2
    DPP_STEP_MAX(x, 0x141);  // row_half_mirror
    DPP_STEP_MAX(x, 0x140);  // row_mirror
    return x;
}
__device__ __forceinline__ float red16_sum(float x) {
    DPP_STEP_SUM(x, 0xB1);
    DPP_STEP_SUM(x, 0x4E);
    DPP_STEP_SUM(x, 0x141);
    DPP_STEP_SUM(x, 0x140);
    return x;
}

// ---- fragment layout in ws (shorts) ---- (unchanged from R5)
#define HEADBASE 86016
#define FRAG_TOTAL 92160

extern "C" __global__ void __launch_bounds__(256)
init_frags(const float* __restrict__ Wz, const float* __restrict__ Wr,
           const float* __restrict__ Wh, const float* __restrict__ Wq,
           const float* __restrict__ Wp, short* __restrict__ frag)
{
    int idx = blockIdx.x * 256 + threadIdx.x;
    if (idx >= FRAG_TOTAL) return;
    float v;
    if (idx < HEADBASE) {
        int T = idx / 3584; int rem = idx - T * 3584;
        int s = rem >> 9;   int e = rem & 511;
        int l = e >> 3, j = e & 7;
        int k = s * 32 + ((l >> 4) << 3) + j;
        int n = ((T & 7) << 4) + (l & 15);
        const float* W = (T < 8) ? Wz : (T < 16) ? Wr : Wh;
        v = (k < KT) ? W[k * HH + n] : 0.f;
    } else {
        int r2 = idx - HEADBASE;
        int ts = r2 >> 9; int e = r2 & 511;
        int t = ts >> 2, s = ts & 3;
        int l = e >> 3, j = e & 7;
        int k = s * 32 + ((l >> 4) << 3) + j;     // < 128
        int c = (t << 4) + (l & 15);
        v = (c < NN) ? Wq[k * NN + c] : (c == NN ? Wp[k] : 0.f);
    }
    frag[idx] = f2bf(v);
}

extern "C" __global__ void __launch_bounds__(1024, 4)
laminar_kernel(const float* __restrict__ packed,
               const float* __restrict__ Wl4,
               const float* __restrict__ Wl23,
               const float* __restrict__ Wsom,
               const float* __restrict__ bz,
               const float* __restrict__ br,
               const float* __restrict__ bh,
               const float* __restrict__ bq,
               const float* __restrict__ bp,
               const short* __restrict__ frag,
               float* __restrict__ out)
{
    const int tid  = threadIdx.x;
    const int r0   = blockIdx.x * RPB;
    const int lane = tid & 63;
    const int w    = tid >> 6;           // 0..15
    const int m    = lane & 15;
    const int q    = lane >> 4;
    // A rows 0..7 = (batch,part): row = batch*2+part; rows 8..15 duplicate.
    // In-lane hi/lo combine: batch b0i = acc[0]+acc[1], b1i = acc[2]+acc[3].
    const int arow = m & 7;
    const int ab   = arow >> 1;          // batch row 0..3
    const int ap   = arow & 1;           // 0: hi part, 1: lo part
    const int b0i  = (q & 1) << 1;       // epilogue batch (lanes<32)
    const int b1i  = b0i + 1;

    __shared__ __align__(16) short xa[2][RPB][KP];   // [part][batch][k]: z/r A
    __shared__ __align__(16) short xb[2][RPB][KP];   // hh A (cols 64+ used)
    __shared__ __align__(16) short hbS[2][RPB][HSTR]; // head A: h_new
    __shared__ float hS[HH][S2];      // h state, [feature][row]
    __shared__ float zgS[HH][S2];     // z gate
    __shared__ float preq[48][S2];    // head pre-acts, [col][row]
    // ring weights chunk-major: [(c*36+i)*4 + d] = W[i][4c+d]
    __shared__ __align__(16) float W4l4[1296], W4l23[1296], W4som[1296];
    __shared__ __align__(16) float l4s[RPB][NPAD], l23s[RPB][NPAD];
    __shared__ __align__(16) float soms[RPB][NPAD], adL[RPB][NPAD];
    __shared__ __align__(16) float l4part[RPB][NPAD];   // stim+Wl4*l4-adapt pipeline
    __shared__ __align__(16) float l23dotS[RPB][NPAD];  // Wl23*l23(t-1)
    __shared__ __align__(16) float somdotS[RPB][NPAD];  // Wsom*som(t-1)
    __shared__ float bzL[HH], brL[HH], bhL[HH], bqL[48];
    __shared__ float pvL[RPB];
    __shared__ float bpS;

    // ---- one-time init ----
    for (int i = tid; i < HH; i += 1024) { bzL[i] = bz[i]; brL[i] = br[i]; bhL[i] = bh[i]; }
    for (int i = tid; i < 48; i += 1024) bqL[i] = (i < NN) ? bq[i] : 0.f;
    if (tid == 0) bpS = bp[0];
    for (int idx = tid; idx < 324; idx += 1024) {
        const int c = idx / NN, i = idx - c * NN;
        const int o = idx * 4;
        #pragma unroll
        for (int d = 0; d < 4; ++d) {
            W4l4[o + d]  = Wl4[i * NN + 4 * c + d];
            W4l23[o + d] = Wl23[i * NN + 4 * c + d];
            W4som[o + d] = Wsom[i * NN + 4 * c + d];
        }
    }
    { short* p = (short*)xa;  for (int i = tid; i < 2*RPB*KP;   i += 1024) p[i] = 0; }
    { short* p = (short*)xb;  for (int i = tid; i < 2*RPB*KP;   i += 1024) p[i] = 0; }
    { short* p = (short*)hbS; for (int i = tid; i < 2*RPB*HSTR; i += 1024) p[i] = 0; }
    { float* p = (float*)hS;  for (int i = tid; i < HH*S2;      i += 1024) p[i] = 0.f; }
    { float* p = (float*)l4s; for (int i = tid; i < RPB*NPAD;   i += 1024) {
        p[i] = 0.f; ((float*)l23s)[i] = 0.f; ((float*)soms)[i] = 0.f;
        ((float*)adL)[i] = 0.f; ((float*)l23dotS)[i] = 0.f; ((float*)somdotS)[i] = 0.f; } }
    if (tid < RPB) pvL[tid] = 0.f;

    // ---- persistent weight fragments (split across wave groups) ----
    bf16x8 FA[7], FB[7];
    if (w < 8) {
        const short* a0 = frag + (w * 7) * 512 + lane * 8;          // Wz tile w
        const short* b0 = frag + ((8 + w) * 7) * 512 + lane * 8;    // Wr tile w
        #pragma unroll
        for (int s = 0; s < 7; ++s) {
            FA[s] = *(const bf16x8*)(a0 + s * 512);
            FB[s] = *(const bf16x8*)(b0 + s * 512);
        }
    } else {
        const int hw8 = w - 8;
        const short* a0 = frag + ((16 + hw8) * 7) * 512 + lane * 8; // Wh tile
        #pragma unroll
        for (int s = 0; s < 7; ++s) FA[s] = *(const bf16x8*)(a0 + s * 512);
        const int hw = (hw8 < 3) ? hw8 : 0;
        const short* b0 = frag + HEADBASE + (hw * 4) * 512 + lane * 8;
        #pragma unroll
        for (int s = 0; s < 4; ++s) FB[s] = *(const bf16x8*)(b0 + s * 512);
        FB[4] = FA[4]; FB[5] = FA[5]; FB[6] = FA[6];   // unused, keep defined
    }

    // ---- aux role assignment ----
    // P1 l23dot: w13-15 (144 threads)
    const int  idA = (w - 13) * 64 + lane;
    const bool isDotA = (w >= 13) && (idA < 144);
    const int  vA = isDotA ? idA : 0;
    const int  drA = vA / 36, diA = vA - drA * 36;
    // P1 l4 finalize + stim: w8-12 lanes>=32 (144 of 160)
    const int  idB = (w - 8) * 32 + (lane - 32);
    const bool isL4f = (w >= 8 && w < 13) && (lane >= 32) && (idB < 144);
    const int  vB = isL4f ? idB : 0;
    const int  lr = vB / 36, li = vB - lr * 36;
    // P3 l4part dot-add: w0-2
    const int  idC = w * 64 + lane;
    const bool isL4p = (w < 3) && (idC < 144);
    const int  vC = isL4p ? idC : 0;
    const int  prD = vC / 36, piD = vC - prD * 36;
    // P3 somdot: w3-5
    const int  idD = (w - 3) * 64 + lane;
    const bool isDotC = (w >= 3 && w < 6) && (idD < 144);
    const int  vD = isDotC ? idD : 0;
    const int  crC = vD / 36, ciC = vD - crC * 36;
    // P3 cue->xa: w7 lanes<52 (3 cols each); P5 cue->xb: w11 lanes<40 (1 col)
    const bool isCueA = (w == 7) && (lane < 52);
    const int  caR = lane / 13, caC0 = 36 + 3 * (lane - caR * 13);
    const bool isCueB = (w == 11) && (lane < 40);
    const int  cbR = lane / 10, cbC = 64 + (lane - cbR * 10);

    __syncthreads();

    // ---- prologue: stage cue(0), prefetch cue(1)/stim(1), l4part(0)=stim(0) ----
    float cav0 = 0.f, cav1 = 0.f, cav2 = 0.f, cbv = 0.f, stimreg = 0.f;
    if (isCueA) {
        const size_t base0 = ((size_t)(r0 + caR) * TT + 0) * DIN;
        #pragma unroll
        for (int d = 0; d < 3; ++d) {
            const int c = caC0 + d;
            if (c < DIN) {
                const float v = packed[base0 + c];
                const short hi = f2bf(v);
                xa[0][caR][c] = hi; xa[1][caR][c] = f2bf(v - bf2f(hi));
            }
        }
        const size_t base1 = ((size_t)(r0 + caR) * TT + 1) * DIN;
        cav0 = packed[base1 + caC0];
        cav1 = (caC0 + 1 < DIN) ? packed[base1 + caC0 + 1] : 0.f;
        cav2 = (caC0 + 2 < DIN) ? packed[base1 + caC0 + 2] : 0.f;
    }
    if (isCueB) {
        const float v = packed[((size_t)(r0 + cbR) * TT + 0) * DIN + cbC];
        const short hi = f2bf(v);
        xb[0][cbR][cbC] = hi; xb[1][cbR][cbC] = f2bf(v - bf2f(hi));
        cbv = packed[((size_t)(r0 + cbR) * TT + 1) * DIN + cbC];
    }
    if (isL4f) stimreg = packed[((size_t)(r0 + lr) * TT + 1) * DIN + li];
    if (tid < RPB * NN) {
        const int r = tid / NN, i = tid - (tid / NN) * NN;
        l4part[r][i] = packed[((size_t)(r0 + r) * TT + 0) * DIN + i];
    }
    __syncthreads();

    // ---- initial zr partial for t=0 (slabs 2-6: cue(0), h(-1)=0) ----
    f32x4 accA = {0.f,0.f,0.f,0.f}, accB = {0.f,0.f,0.f,0.f};
    if (w < 8) {
        const short* xaRow = &xa[ap][ab][0];
        #pragma unroll
        for (int s = 2; s < 7; ++s) {
            const bf16x8 Ax = *(const bf16x8*)&xaRow[s * 32 + q * 8];
            accA = MFMA(Ax, FA[s], accA);
            accB = MFMA(Ax, FB[s], accB);
        }
    }
    __syncthreads();

    for (int t = 0; t < TT; ++t) {
        // ---- P1: zr finish + epilogue (w0-7) || h start (w8-15)
        //          || l23dot (w13-15) || l4f+stim (w8-12 hi-lanes) ----
        {
            const short* xaRow = &xa[ap][ab][0];
            const bf16x8 A0 = *(const bf16x8*)&xaRow[q * 8];
            const bf16x8 A1 = *(const bf16x8*)&xaRow[32 + q * 8];
            if (w < 8) {
                accA = MFMA(A0, FA[0], accA);
                accB = MFMA(A0, FB[0], accB);
                accA = MFMA(A1, FA[1], accA);
                accB = MFMA(A1, FB[1], accB);
                if (lane < 32) {
                    const int f = w * 16 + m;
                    const float z0 = accA[0] + accA[1], z1 = accA[2] + accA[3];
                    const float r0v = accB[0] + accB[1], r1v = accB[2] + accB[3];
                    zgS[f][b0i] = sigmf(z0 + bzL[f]);
                    zgS[f][b1i] = sigmf(z1 + bzL[f]);
                    const float ra = sigmf(r0v + brL[f]) * hS[f][b0i];
                    const float rb = sigmf(r1v + brL[f]) * hS[f][b1i];
                    const unsigned ph = cvtpk(ra, rb);
                    const unsigned pl = cvtpk(ra - lo16f(ph), rb - hi16f(ph));
                    xb[0][b0i][DIN + f] = (short)ph;         xb[1][b0i][DIN + f] = (short)pl;
                    xb[0][b1i][DIN + f] = (short)(ph >> 16); xb[1][b1i][DIN + f] = (short)(pl >> 16);
                }
            } else {
                const f32x4 z4 = {0.f,0.f,0.f,0.f};
                accA = MFMA(A0, FA[0], z4);
                accB = MFMA(A1, FA[1], z4);
            }
        }
        if (isDotA) {                          // l23dot from l23(t-1)
            float acc = 0.f;
            #pragma unroll
            for (int c = 0; c < 9; ++c) {
                const float4 wv = *(const float4*)&W4l23[(c * NN + diA) * 4];
                const float4 sv = *(const float4*)&l23s[drA][4 * c];
                acc += sv.x*wv.x + sv.y*wv.y + sv.z*wv.z + sv.w*wv.w;
            }
            l23dotS[drA][diA] = acc;
        }
        if (isL4f) {                           // l4(t) finalize; l4part(t+1) base
            const float nl4 = 0.9f * l4s[lr][li]
                            + 0.1f * fmaxf(l4part[lr][li] - pvL[lr], 0.f);
            l4s[lr][li] = nl4;
            const float ad = 0.98f * adL[lr][li] + 0.01f * nl4;
            adL[lr][li] = ad;
            l4part[lr][li] = stimreg - ad;     // stim(t+1) - adapt(t)
            const int tn = (t + 2 < TT) ? t + 2 : TT - 1;
            stimreg = packed[((size_t)(r0 + lr) * TT + tn) * DIN + li];
        }
        BAR();

        // ---- P3: h finish + epilogue (w8-15) || l4part-dot (w0-2)
        //          || somdot (w3-5) || PV (w6) || cue->xa (w7) ----
        if (w >= 8) {
            const short* xbRow = &xb[ap][ab][0];
            bf16x8 Op[5];
            #pragma unroll
            for (int s = 0; s < 5; ++s)
                Op[s] = *(const bf16x8*)&xbRow[(s + 2) * 32 + q * 8];
            accA = MFMA(Op[0], FA[2], accA);
            accB = MFMA(Op[1], FA[3], accB);
            accA = MFMA(Op[2], FA[4], accA);
            accB = MFMA(Op[3], FA[5], accB);
            accA = MFMA(Op[4], FA[6], accA);
            const f32x4 a = accA + accB;
            if (lane < 32) {
                const int f = (w - 8) * 16 + m;
                const float s0 = a[0] + a[1], s1 = a[2] + a[3];
                const float hh0 = tanhf_fast(s0 + bhL[f]);
                const float hh1 = tanhf_fast(s1 + bhL[f]);
                const float zg0 = zgS[f][b0i], zg1 = zgS[f][b1i];
                const float hn0 = (1.0f - zg0) * hS[f][b0i] + zg0 * hh0;
                const float hn1 = (1.0f - zg1) * hS[f][b1i] + zg1 * hh1;
                hS[f][b0i] = hn0; hS[f][b1i] = hn1;
                const unsigned ph = cvtpk(hn0, hn1);
                const unsigned pl = cvtpk(hn0 - lo16f(ph), hn1 - hi16f(ph));
                hbS[0][b0i][f] = (short)ph;         hbS[1][b0i][f] = (short)pl;
                hbS[0][b1i][f] = (short)(ph >> 16); hbS[1][b1i][f] = (short)(pl >> 16);
                xa[0][b0i][DIN + f] = (short)ph;         xa[1][b0i][DIN + f] = (short)pl;
                xa[0][b1i][DIN + f] = (short)(ph >> 16); xa[1][b1i][DIN + f] = (short)(pl >> 16);
            }
        } else if (isL4p) {                    // l4part(t+1) += Wl4*l4(t)
            float acc = l4part[prD][piD];
            #pragma unroll
            for (int c = 0; c < 9; ++c) {
                const float4 wv = *(const float4*)&W4l4[(c * NN + piD) * 4];
                const float4 sv = *(const float4*)&l4s[prD][4 * c];
                acc += sv.x*wv.x + sv.y*wv.y + sv.z*wv.z + sv.w*wv.w;
            }
            l4part[prD][piD] = acc;
        } else if (isDotC) {                   // somdot from som(t-1)
            float acc = 0.f;
            #pragma unroll
            for (int c = 0; c < 9; ++c) {
                const float4 wv = *(const float4*)&W4som[(c * NN + ciC) * 4];
                const float4 sv = *(const float4*)&soms[crC][4 * c];
                acc += sv.x*wv.x + sv.y*wv.y + sv.z*wv.z + sv.w*wv.w;
            }
            somdotS[crC][ciC] = acc;
        } else if (w == 6) {                   // PV: l4(t) + l23(t-1), DPP reduce
            const int row = q;                 // 0..3
            float s = l4s[row][m] + l23s[row][m] + l4s[row][m + 16] + l23s[row][m + 16];
            if (m < 4) s += l4s[row][m + 32] + l23s[row][m + 32];
            s = red16_sum(s);
            if (m == 0) pvL[row] = 0.9f * pvL[row] + 0.1f * fmaxf(s * (1.0f / 36.0f), 0.f);
        } else if (isCueA) {                   // cue(t+1)->xa; prefetch t+2
            #pragma unroll
            for (int d = 0; d < 3; ++d) {
                const int c = caC0 + d;
                if (c < DIN) {
                    const float v = (d == 0) ? cav0 : (d == 1) ? cav1 : cav2;
                    const short hi = f2bf(v);
                    xa[0][caR][c] = hi; xa[1][caR][c] = f2bf(v - bf2f(hi));
                }
            }
            const int tn = (t + 2 < TT) ? t + 2 : TT - 1;
            const size_t base = ((size_t)(r0 + caR) * TT + tn) * DIN;
            cav0 = packed[base + caC0];
            cav1 = (caC0 + 1 < DIN) ? packed[base + caC0 + 1] : 0.f;
            cav2 = (caC0 + 2 < DIN) ? packed[base + caC0 + 2] : 0.f;
        }
        BAR();

        // ---- P5: zr(t+1) partial (w0-7) || heads (w8-10) || cue->xb (w11) ----
        if (w < 8) {
            const short* xaRow = &xa[ap][ab][0];
            const f32x4 z4 = {0.f,0.f,0.f,0.f};
            accA = z4; accB = z4;
            #pragma unroll
            for (int s = 2; s < 7; ++s) {
                const bf16x8 Ax = *(const bf16x8*)&xaRow[s * 32 + q * 8];
                accA = MFMA(Ax, FA[s], accA);
                accB = MFMA(Ax, FB[s], accB);
            }
        } else if (w < 11) {
            const short* hbRow = &hbS[ap][ab][0];
            f32x4 hd = {0.f,0.f,0.f,0.f};
            #pragma unroll
            for (int s = 0; s < 4; ++s) {
                const bf16x8 Hk = *(const bf16x8*)&hbRow[s * 32 + q * 8];
                hd = MFMA(Hk, FB[s], hd);
            }
            if (lane < 32) {
                const int c = (w - 8) * 16 + m;
                preq[c][b0i] = hd[0] + hd[1];
                preq[c][b1i] = hd[2] + hd[3];
            }
        } else if (isCueB) {                   // cue(t+1)->xb cols 64-73; prefetch
            const short hi = f2bf(cbv);
            xb[0][cbR][cbC] = hi; xb[1][cbR][cbC] = f2bf(cbv - bf2f(hi));
            const int tn = (t + 2 < TT) ? t + 2 : TT - 1;
            cbv = packed[((size_t)(r0 + cbR) * TT + tn) * DIN + cbC];
        }
        BAR();

        // ---- P6: softmax+pi (DPP butterfly) + pointwise SOM/L23 + output ----
        if (w < 4) {
            const int rr = w;   // 0..3
            const float v0 = preq[m][rr] + bqL[m];
            const float v1 = preq[m + 16][rr] + bqL[m + 16];
            const float v2 = (m < 4) ? (preq[m + 32][rr] + bqL[m + 32]) : -1e30f;
            const float pi = sigmf(preq[36][rr] + bpS);
            const float mx = red16_max(fmaxf(fmaxf(v0, v1), v2));
            const float e0 = __expf(v0 - mx);
            const float e1 = __expf(v1 - mx);
            const float e2 = (m < 4) ? __expf(v2 - mx) : 0.f;
            const float ss = red16_sum(e0 + e1 + e2);
            const float sc = fastrcp(ss) * pi;
            if (lane < 16) {
                const float pv = pvL[rr];
                const size_t outb = ((size_t)(r0 + rr) * TT + t) * NN;
                float ln01[2];
                #pragma unroll
                for (int t2 = 0; t2 < 2; ++t2) {
                    const int i = m + 16 * t2;
                    const float dt = (t2 ? e1 : e0) * sc;
                    const float sn = 0.9f * soms[rr][i]
                                   + 0.1f * fmaxf(dt + somdotS[rr][i], 0.f);
                    soms[rr][i] = sn;
                    const float acc2 = (l4s[rr][i] - dt) * (1.0f + 0.5f * dt)
                                     + l23dotS[rr][i] - 0.8f * sn - pv;
                    const float ln = 0.9f * l23s[rr][i] + 0.1f * fmaxf(acc2, 0.f);
                    l23s[rr][i] = ln;
                    out[outb + i] = ln;
                    ln01[t2] = ln;
                }
                const unsigned ph = cvtpk(ln01[0], ln01[1]);
                const unsigned pl = cvtpk(ln01[0] - lo16f(ph), ln01[1] - hi16f(ph));
                xa[0][rr][m]      = (short)ph;         xa[1][rr][m]      = (short)pl;
                xa[0][rr][m + 16] = (short)(ph >> 16); xa[1][rr][m + 16] = (short)(pl >> 16);
                if (m < 4) {
                    const int i = m + 32;
                    const float dt = e2 * sc;
                    const float sn = 0.9f * soms[rr][i]
                                   + 0.1f * fmaxf(dt + somdotS[rr][i], 0.f);
                    soms[rr][i] = sn;
                    const float acc2 = (l4s[rr][i] - dt) * (1.0f + 0.5f * dt)
                                     + l23dotS[rr][i] - 0.8f * sn - pv;
                    const float ln = 0.9f * l23s[rr][i] + 0.1f * fmaxf(acc2, 0.f);
                    l23s[rr][i] = ln;
                    out[outb + i] = ln;
                    const short hi2 = f2bf(ln);
                    xa[0][rr][i] = hi2; xa[1][rr][i] = f2bf(ln - bf2f(hi2));
                }
            }
        }
        BAR();
    }
}

extern "C" void kernel_launch(void* const* d_in, const int* in_sizes, int n_in,
                              void* d_out, int out_size, void* d_ws, size_t ws_size,
                              hipStream_t stream) {
    (void)in_sizes; (void)n_in; (void)out_size; (void)ws_size;
    const float* packed = (const float*)d_in[0];
    const float* Wl4    = (const float*)d_in[1];
    const float* Wl23   = (const float*)d_in[2];
    const float* Wsom   = (const float*)d_in[3];
    const float* Wz     = (const float*)d_in[4];
    const float* Wr     = (const float*)d_in[5];
    const float* Wh     = (const float*)d_in[6];
    const float* bz     = (const float*)d_in[7];
    const float* br     = (const float*)d_in[8];
    const float* bh     = (const float*)d_in[9];
    const float* Wq     = (const float*)d_in[10];
    const float* bq     = (const float*)d_in[11];
    const float* Wp     = (const float*)d_in[12];
    const float* bp     = (const float*)d_in[13];
    float* out  = (float*)d_out;
    short* frag = (short*)d_ws;   // needs 184320 B

    init_frags<<<(FRAG_TOTAL + 255) / 256, 256, 0, stream>>>(Wz, Wr, Wh, Wq, Wp, frag);
    laminar_kernel<<<256, 1024, 0, stream>>>(packed, Wl4, Wl23, Wsom,
                                             bz, br, bh, bq, bp, frag, out);
}

// Round 5
// 1416.223 us; speedup vs baseline: 1.2601x; 1.2601x over previous
//
#include <hip/hip_runtime.h>
#include <cstdint>
#include <cstddef>

// LaminarV1V2Network: B=1024, T=512, N=36, H=128, D_in=74, K=202.
// R9 = R7 (known-good 1410us) + three minimal-delta changes:
//  (a) l4-finalize + stim prefetch moved P1 -> P6 (runs parallel to softmax
//      on idle waves w8-10) with parity-double-buffered l4s[2] (pointwise
//      reads l4s[t&1], l4f writes l4s[(t+1)&1]). Removes ~3 serial LDS
//      round-trips from the heaviest phase.
//  (b) ring weights chunk-major W4*[(c*36+i)*4+d] (verified in R8):
//      conflict-free float4 dot reads.
//  (c) z-gate sigmoid deferred to P3 epilogue (zgS holds pre-act+bias):
//      balances P1/P3 transcendental load.
// Structure otherwise identical to R7: 256 blocks x 1024 threads (16 waves),
// RPB=4, frag split w0-7={Wz,Wr} / w8-15={Wh,head}, 8-row A packing
// (row=batch*2+part, in-lane hi/lo combine, no shfl), KP=232, HSTR=136,
// 4 lgkm-only barriers/step.

#define NN   36
#define HH   128
#define DIN  74
#define KT   202
#define KP   232      // row = 116 words == 20 mod 32 -> 8-row map bank-uniform
#define TT   512
#define RPB  4
#define NPAD 40
#define HSTR 136      // hb row stride (shorts): 68 words == 4 mod 32 -> bank-uniform
#define S2   6        // second-dim stride for hS/zgS/preq

typedef short bf16x8 __attribute__((ext_vector_type(8)));
typedef float f32x4  __attribute__((ext_vector_type(4)));

#define MFMA(a,b,c) __builtin_amdgcn_mfma_f32_16x16x32_bf16((a),(b),(c),0,0,0)
// Barrier that orders LDS only: global loads/stores float across it.
#define BAR() asm volatile("s_waitcnt lgkmcnt(0)\n\ts_barrier" ::: "memory")

__device__ __forceinline__ float fastrcp(float x) { return __builtin_amdgcn_rcpf(x); }
__device__ __forceinline__ float sigmf(float x) { return fastrcp(1.0f + __expf(-x)); }
__device__ __forceinline__ float tanhf_fast(float x) {
    return 1.0f - 2.0f * fastrcp(1.0f + __expf(2.0f * x));
}

__device__ __forceinline__ short f2bf(float v) {
    union { float f; unsigned u; } x; x.f = v;
    unsigned r = (x.u + 0x7fffu + ((x.u >> 16) & 1u)) >> 16;   // RNE
    return (short)r;
}
__device__ __forceinline__ float bf2f(short s) {
    union { unsigned u; float f; } y; y.u = ((unsigned)(unsigned short)s) << 16;
    return y.f;
}

// v_cvt_pk_bf16_f32: dst[15:0]=bf16(a), dst[31:16]=bf16(b), RNE (same as f2bf).
__device__ __forceinline__ unsigned cvtpk(float a, float b) {
    unsigned r;
    asm("v_cvt_pk_bf16_f32 %0, %1, %2" : "=v"(r) : "v"(a), "v"(b));
    return r;
}
__device__ __forceinline__ float lo16f(unsigned p) { return __uint_as_float(p << 16); }
__device__ __forceinline__ float hi16f(unsigned p) { return __uint_as_float(p & 0xffff0000u); }

// 16-lane butterfly reduction at VALU speed via DPP.
#define DPP_STEP_MAX(x, ctrl) \
    x = fmaxf(x, __int_as_float(__builtin_amdgcn_update_dpp(0, __float_as_int(x), (ctrl), 0xF, 0xF, true)))
#define DPP_STEP_SUM(x, ctrl) \
    x = x + __int_as_float(__builtin_amdgcn_update_dpp(0, __float_as_int(x), (ctrl), 0xF, 0xF, true))

__device__ __forceinline__ float red16_max(float x) {
    DPP_STEP_MAX(x, 0xB1);   // quad_perm xor1
    DPP_STEP_MAX(x, 0x4E);   // quad_perm xor2
    DPP_STEP_MAX(x, 0x141);  // row_half_mirror
    DPP_STEP_MAX(x, 0x140);  // row_mirror
    return x;
}
__device__ __forceinline__ float red16_sum(float x) {
    DPP_STEP_SUM(x, 0xB1);
    DPP_STEP_SUM(x, 0x4E);
    DPP_STEP_SUM(x, 0x141);
    DPP_STEP_SUM(x, 0x140);
    return x;
}

// ---- fragment layout in ws (shorts) ---- (unchanged from R5)
#define HEADBASE 86016
#define FRAG_TOTAL 92160

extern "C" __global__ void __launch_bounds__(256)
init_frags(const float* __restrict__ Wz, const float* __restrict__ Wr,
           const float* __restrict__ Wh, const float* __restrict__ Wq,
           const float* __restrict__ Wp, short* __restrict__ frag)
{
    int idx = blockIdx.x * 256 + threadIdx.x;
    if (idx >= FRAG_TOTAL) return;
    float v;
    if (idx < HEADBASE) {
        int T = idx / 3584; int rem = idx - T * 3584;
        int s = rem >> 9;   int e = rem & 511;
        int l = e >> 3, j = e & 7;
        int k = s * 32 + ((l >> 4) << 3) + j;
        int n = ((T & 7) << 4) + (l & 15);
        const float* W = (T < 8) ? Wz : (T < 16) ? Wr : Wh;
        v = (k < KT) ? W[k * HH + n] : 0.f;
    } else {
        int r2 = idx - HEADBASE;
        int ts = r2 >> 9; int e = r2 & 511;
        int t = ts >> 2, s = ts & 3;
        int l = e >> 3, j = e & 7;
        int k = s * 32 + ((l >> 4) << 3) + j;     // < 128
        int c = (t << 4) + (l & 15);
        v = (c < NN) ? Wq[k * NN + c] : (c == NN ? Wp[k] : 0.f);
    }
    frag[idx] = f2bf(v);
}

extern "C" __global__ void __launch_bounds__(1024, 4)
laminar_kernel(const float* __restrict__ packed,
               const float* __restrict__ Wl4,
               const float* __restrict__ Wl23,
               const float* __restrict__ Wsom,
               const float* __restrict__ bz,
               const float* __restrict__ br,
               const float* __restrict__ bh,
               const float* __restrict__ bq,
               const float* __restrict__ bp,
               const short* __restrict__ frag,
               float* __restrict__ out)
{
    const int tid  = threadIdx.x;
    const int r0   = blockIdx.x * RPB;
    const int lane = tid & 63;
    const int w    = tid >> 6;           // 0..15
    const int m    = lane & 15;
    const int q    = lane >> 4;
    // A rows 0..7 = (batch,part): row = batch*2+part; rows 8..15 duplicate.
    // In-lane hi/lo combine: batch b0i = acc[0]+acc[1], b1i = acc[2]+acc[3].
    const int arow = m & 7;
    const int ab   = arow >> 1;          // batch row 0..3
    const int ap   = arow & 1;           // 0: hi part, 1: lo part
    const int b0i  = (q & 1) << 1;       // epilogue batch (lanes<32)
    const int b1i  = b0i + 1;

    __shared__ __align__(16) short xa[2][RPB][KP];   // [part][batch][k]: z/r A
    __shared__ __align__(16) short xb[2][RPB][KP];   // hh A (cols 64+ used)
    __shared__ __align__(16) short hbS[2][RPB][HSTR]; // head A: h_new
    __shared__ float hS[HH][S2];      // h state, [feature][row]
    __shared__ float zgS[HH][S2];     // z gate PRE-ACT (+bias); sigmoid in P3
    __shared__ float preq[48][S2];    // head pre-acts, [col][row]
    // ring weights chunk-major: [(c*36+i)*4 + d] = W[i][4c+d]
    __shared__ __align__(16) float W4l4[1296], W4l23[1296], W4som[1296];
    __shared__ __align__(16) float l4s[2][RPB][NPAD];   // parity: cur=t&1
    __shared__ __align__(16) float l23s[RPB][NPAD];
    __shared__ __align__(16) float soms[RPB][NPAD], adL[RPB][NPAD];
    __shared__ __align__(16) float l4part[RPB][NPAD];   // stim+Wl4*l4-adapt pipeline
    __shared__ __align__(16) float l23dotS[RPB][NPAD];  // Wl23*l23(t-1)
    __shared__ __align__(16) float somdotS[RPB][NPAD];  // Wsom*som(t-1)
    __shared__ float bzL[HH], brL[HH], bhL[HH], bqL[48];
    __shared__ float pvL[RPB];
    __shared__ float bpS;

    // ---- one-time init ----
    for (int i = tid; i < HH; i += 1024) { bzL[i] = bz[i]; brL[i] = br[i]; bhL[i] = bh[i]; }
    for (int i = tid; i < 48; i += 1024) bqL[i] = (i < NN) ? bq[i] : 0.f;
    if (tid == 0) bpS = bp[0];
    for (int idx = tid; idx < 324; idx += 1024) {
        const int c = idx / NN, i = idx - c * NN;
        const int o = idx * 4;
        #pragma unroll
        for (int d = 0; d < 4; ++d) {
            W4l4[o + d]  = Wl4[i * NN + 4 * c + d];
            W4l23[o + d] = Wl23[i * NN + 4 * c + d];
            W4som[o + d] = Wsom[i * NN + 4 * c + d];
        }
    }
    { short* p = (short*)xa;  for (int i = tid; i < 2*RPB*KP;   i += 1024) p[i] = 0; }
    { short* p = (short*)xb;  for (int i = tid; i < 2*RPB*KP;   i += 1024) p[i] = 0; }
    { short* p = (short*)hbS; for (int i = tid; i < 2*RPB*HSTR; i += 1024) p[i] = 0; }
    { float* p = (float*)hS;  for (int i = tid; i < HH*S2;      i += 1024) p[i] = 0.f; }
    { float* p = (float*)l4s; for (int i = tid; i < 2*RPB*NPAD; i += 1024) p[i] = 0.f; }
    { float* p = (float*)l23s; for (int i = tid; i < RPB*NPAD;  i += 1024) {
        p[i] = 0.f; ((float*)soms)[i] = 0.f; ((float*)adL)[i] = 0.f;
        ((float*)l23dotS)[i] = 0.f; ((float*)somdotS)[i] = 0.f; } }
    if (tid < RPB) pvL[tid] = 0.f;

    // ---- persistent weight fragments (split across wave groups) ----
    bf16x8 FA[7], FB[7];
    if (w < 8) {
        const short* a0 = frag + (w * 7) * 512 + lane * 8;          // Wz tile w
        const short* b0 = frag + ((8 + w) * 7) * 512 + lane * 8;    // Wr tile w
        #pragma unroll
        for (int s = 0; s < 7; ++s) {
            FA[s] = *(const bf16x8*)(a0 + s * 512);
            FB[s] = *(const bf16x8*)(b0 + s * 512);
        }
    } else {
        const int hw8 = w - 8;
        const short* a0 = frag + ((16 + hw8) * 7) * 512 + lane * 8; // Wh tile
        #pragma unroll
        for (int s = 0; s < 7; ++s) FA[s] = *(const bf16x8*)(a0 + s * 512);
        const int hw = (hw8 < 3) ? hw8 : 0;
        const short* b0 = frag + HEADBASE + (hw * 4) * 512 + lane * 8;
        #pragma unroll
        for (int s = 0; s < 4; ++s) FB[s] = *(const bf16x8*)(b0 + s * 512);
        FB[4] = FA[4]; FB[5] = FA[5]; FB[6] = FA[6];   // unused, keep defined
    }

    // ---- aux role assignment ----
    // P1 l23dot: w13-15 (144 threads)
    const int  idA = (w - 13) * 64 + lane;
    const bool isDotA = (w >= 13) && (idA < 144);
    const int  vA = idA < 144 ? (idA < 0 ? 0 : idA) : 0;
    const int  drA = (isDotA ? vA : 0) / 36, diA = (isDotA ? vA : 0) - drA * 36;
    const float* dAW = W4l23 + diA * 4;
    const float* dAS = &l23s[drA][0];
    float*       dAD = &l23dotS[drA][diA];
    // P6 l4 finalize + stim: w8-10 (144 threads)
    const int  idB = (w - 8) * 64 + lane;
    const bool isL4f = (w >= 8 && w < 11) && (idB < 144);
    const int  vB = isL4f ? idB : 0;
    const int  lr = vB / 36, li = vB - lr * 36;
    // P3 somdot: w0-2
    const int  idC = w * 64 + lane;
    const bool isDotC = (w < 3) && (idC < 144);
    const int  vC = isDotC ? idC : 0;
    const int  crC = vC / 36, ciC = vC - crC * 36;
    const float* dCW = W4som + ciC * 4;
    const float* dCS = &soms[crC][0];
    float*       dCD = &somdotS[crC][ciC];
    // P5 l4part dot-add: w3-5
    const int  idD = (w - 3) * 64 + lane;
    const bool isL4p = (w >= 3 && w < 6) && (idD < 144);
    const int  vD = isL4p ? idD : 0;
    const int  prD = vD / 36, piD = vD - prD * 36;
    const float* pW = W4l4 + piD * 4;
    // P5 cue/task staging on w6-7 (4 rows x 19 thr x 2 cols)
    const int  idE = (w - 6) * 64 + lane;
    const bool isCue = (w >= 6 && w < 8) && (idE < 76);
    const int  evE = isCue ? idE : 0;
    const int  ctr = evE / 19;
    const int  ctc = 36 + 2 * (evE - ctr * 19);   // 36..72 even

    __syncthreads();   // zero-init complete before prologue overwrites

    // ---- prologue ----
    // l4(0) = 0.1*relu(stim(0)); adapt(0) = 0.01*l4(0);
    // l4part = stim(1) - adapt(0)  (base for t=1; P5(0) adds Wl4*l4(0))
    float ctv0 = 0.f, ctv1 = 0.f, stimreg = 0.f;
    if (tid < RPB * NN) {
        const int r = tid / NN, i = tid - (tid / NN) * NN;
        const size_t b = ((size_t)(r0 + r) * TT) * DIN + i;
        const float s0 = packed[b];
        const float nl4 = 0.1f * fmaxf(s0, 0.f);
        l4s[0][r][i] = nl4;
        const float ad = 0.01f * nl4;
        adL[r][i] = ad;
        l4part[r][i] = packed[b + DIN] - ad;
    }
    if (isL4f) stimreg = packed[((size_t)(r0 + lr) * TT + 2) * DIN + li];
    if (isCue) {
        const size_t base0 = ((size_t)(r0 + ctr) * TT + 0) * DIN;
        #pragma unroll
        for (int d = 0; d < 2; ++d) {
            const float v = packed[base0 + ctc + d];
            const short hi = f2bf(v), lo = f2bf(v - bf2f(hi));
            xa[0][ctr][ctc + d] = hi; xa[1][ctr][ctc + d] = lo;
            if (ctc + d >= 64) { xb[0][ctr][ctc + d] = hi; xb[1][ctr][ctc + d] = lo; }
        }
        const size_t base1 = ((size_t)(r0 + ctr) * TT + 1) * DIN;
        ctv0 = packed[base1 + ctc]; ctv1 = packed[base1 + ctc + 1];
    }
    __syncthreads();

    for (int t = 0; t < TT; ++t) {
        float (*l4cur)[NPAD] = l4s[t & 1];
        float (*l4nxt)[NPAD] = l4s[(t + 1) & 1];

        // ---- P1: z/r gemm (w0-7) || l23dot (w13-15) ----
        if (w < 8) {
            const short* xaRow = &xa[ap][ab][0];
            bf16x8 Ax[7];
            #pragma unroll
            for (int s = 0; s < 7; ++s)
                Ax[s] = *(const bf16x8*)&xaRow[s * 32 + q * 8];
            f32x4 az = {0.f,0.f,0.f,0.f}, ar = {0.f,0.f,0.f,0.f};
            #pragma unroll
            for (int s = 0; s < 7; ++s) {
                az = MFMA(Ax[s], FA[s], az);
                ar = MFMA(Ax[s], FB[s], ar);
            }
            if (lane < 32) {
                const int f = w * 16 + m;
                const float z0 = az[0] + az[1], z1 = az[2] + az[3];
                const float r0v = ar[0] + ar[1], r1v = ar[2] + ar[3];
                zgS[f][b0i] = z0 + bzL[f];         // pre-act; sigmoid in P3
                zgS[f][b1i] = z1 + bzL[f];
                const float ra = sigmf(r0v + brL[f]) * hS[f][b0i];
                const float rb = sigmf(r1v + brL[f]) * hS[f][b1i];
                const unsigned ph = cvtpk(ra, rb);
                const unsigned pl = cvtpk(ra - lo16f(ph), rb - hi16f(ph));
                xb[0][b0i][DIN + f] = (short)ph;         xb[1][b0i][DIN + f] = (short)pl;
                xb[0][b1i][DIN + f] = (short)(ph >> 16); xb[1][b1i][DIN + f] = (short)(pl >> 16);
            }
        } else if (isDotA) {                   // l23dot from l23(t-1)
            float acc = 0.f;
            #pragma unroll
            for (int c = 0; c < 9; ++c) {
                const float4 wv = *(const float4*)&dAW[c * 144];
                const float4 sv = *(const float4*)&dAS[4 * c];
                acc += sv.x*wv.x + sv.y*wv.y + sv.z*wv.z + sv.w*wv.w;
            }
            *dAD = acc;
        }
        BAR();

        // ---- P3: h gemm (w8-15) || somdot (w0-2) || PV (w6) ----
        if (w >= 8) {
            const short* xaRow = &xa[ap][ab][0];
            const short* xbRow = &xb[ap][ab][0];
            bf16x8 Op[7];
            Op[0] = *(const bf16x8*)&xaRow[q * 8];
            Op[1] = *(const bf16x8*)&xaRow[32 + q * 8];
            #pragma unroll
            for (int s = 2; s < 7; ++s)
                Op[s] = *(const bf16x8*)&xbRow[s * 32 + q * 8];
            f32x4 a = {0.f,0.f,0.f,0.f}, b = {0.f,0.f,0.f,0.f};
            a = MFMA(Op[0], FA[0], a);
            b = MFMA(Op[1], FA[1], b);
            a = MFMA(Op[2], FA[2], a);
            b = MFMA(Op[3], FA[3], b);
            a = MFMA(Op[4], FA[4], a);
            b = MFMA(Op[5], FA[5], b);
            a = MFMA(Op[6], FA[6], a);
            a = a + b;
            if (lane < 32) {
                const int f = (w - 8) * 16 + m;
                const float s0 = a[0] + a[1], s1 = a[2] + a[3];
                const float hh0 = tanhf_fast(s0 + bhL[f]);
                const float hh1 = tanhf_fast(s1 + bhL[f]);
                const float zg0 = sigmf(zgS[f][b0i]);
                const float zg1 = sigmf(zgS[f][b1i]);
                const float hn0 = (1.0f - zg0) * hS[f][b0i] + zg0 * hh0;
                const float hn1 = (1.0f - zg1) * hS[f][b1i] + zg1 * hh1;
                hS[f][b0i] = hn0; hS[f][b1i] = hn1;
                const unsigned ph = cvtpk(hn0, hn1);
                const unsigned pl = cvtpk(hn0 - lo16f(ph), hn1 - hi16f(ph));
                hbS[0][b0i][f] = (short)ph;         hbS[1][b0i][f] = (short)pl;
                hbS[0][b1i][f] = (short)(ph >> 16); hbS[1][b1i][f] = (short)(pl >> 16);
                xa[0][b0i][DIN + f] = (short)ph;         xa[1][b0i][DIN + f] = (short)pl;
                xa[0][b1i][DIN + f] = (short)(ph >> 16); xa[1][b1i][DIN + f] = (short)(pl >> 16);
            }
        } else if (isDotC) {                   // somdot from som(t-1)
            float acc = 0.f;
            #pragma unroll
            for (int c = 0; c < 9; ++c) {
                const float4 wv = *(const float4*)&dCW[c * 144];
                const float4 sv = *(const float4*)&dCS[4 * c];
                acc += sv.x*wv.x + sv.y*wv.y + sv.z*wv.z + sv.w*wv.w;
            }
            *dCD = acc;
        } else if (w == 6) {                   // PV: l4(t) + l23(t-1), DPP reduce
            const int row = q;                 // 0..3
            float s = l4cur[row][m] + l23s[row][m] + l4cur[row][m + 16] + l23s[row][m + 16];
            if (m < 4) s += l4cur[row][m + 32] + l23s[row][m + 32];
            s = red16_sum(s);
            if (m == 0) pvL[row] = 0.9f * pvL[row] + 0.1f * fmaxf(s * (1.0f / 36.0f), 0.f);
        }
        BAR();

        // ---- P5: heads (w8-10) || l4part-add (w3-5) || cue (w6-7) ----
        if (w >= 8 && w < 11) {
            const short* hbRow = &hbS[ap][ab][0];
            bf16x8 Hk[4];
            #pragma unroll
            for (int s = 0; s < 4; ++s)
                Hk[s] = *(const bf16x8*)&hbRow[s * 32 + q * 8];
            f32x4 a = {0.f,0.f,0.f,0.f};
            #pragma unroll
            for (int s = 0; s < 4; ++s) a = MFMA(Hk[s], FB[s], a);
            if (lane < 32) {
                const int c = (w - 8) * 16 + m;
                preq[c][b0i] = a[0] + a[1];
                preq[c][b1i] = a[2] + a[3];
            }
        } else if (isL4p) {                    // l4part(t+1) += Wl4*l4(t)
            const float* pS = &l4cur[prD][0];
            float acc = l4part[prD][piD];
            #pragma unroll
            for (int c = 0; c < 9; ++c) {
                const float4 wv = *(const float4*)&pW[c * 144];
                const float4 sv = *(const float4*)&pS[4 * c];
                acc += sv.x*wv.x + sv.y*wv.y + sv.z*wv.z + sv.w*wv.w;
            }
            l4part[prD][piD] = acc;
        } else if (isCue) {                    // cue/task(t+1) -> LDS; prefetch t+2
            const unsigned ph = cvtpk(ctv0, ctv1);
            const unsigned pl = cvtpk(ctv0 - lo16f(ph), ctv1 - hi16f(ph));
            xa[0][ctr][ctc]     = (short)ph;         xa[1][ctr][ctc]     = (short)pl;
            xa[0][ctr][ctc + 1] = (short)(ph >> 16); xa[1][ctr][ctc + 1] = (short)(pl >> 16);
            if (ctc >= 64) {   // ctc even, so ctc>=64 <=> ctc+1>=64
                xb[0][ctr][ctc]     = (short)ph;         xb[1][ctr][ctc]     = (short)pl;
                xb[0][ctr][ctc + 1] = (short)(ph >> 16); xb[1][ctr][ctc + 1] = (short)(pl >> 16);
            }
            const int tn = (t + 2 < TT) ? t + 2 : TT - 1;
            const size_t base = ((size_t)(r0 + ctr) * TT + tn) * DIN;
            ctv0 = packed[base + ctc]; ctv1 = packed[base + ctc + 1];
        }
        BAR();

        // ---- P6: softmax+pointwise (w0-3) || l4-finalize+stim (w8-10) ----
        if (w < 4) {
            const int rr = w;   // 0..3
            const float v0 = preq[m][rr] + bqL[m];
            const float v1 = preq[m + 16][rr] + bqL[m + 16];
            const float v2 = (m < 4) ? (preq[m + 32][rr] + bqL[m + 32]) : -1e30f;
            const float pi = sigmf(preq[36][rr] + bpS);
            const float mx = red16_max(fmaxf(fmaxf(v0, v1), v2));
            const float e0 = __expf(v0 - mx);
            const float e1 = __expf(v1 - mx);
            const float e2 = (m < 4) ? __expf(v2 - mx) : 0.f;
            const float ss = red16_sum(e0 + e1 + e2);
            const float sc = fastrcp(ss) * pi;
            if (lane < 16) {
                const float pv = pvL[rr];
                const size_t outb = ((size_t)(r0 + rr) * TT + t) * NN;
                float ln01[2];
                #pragma unroll
                for (int t2 = 0; t2 < 2; ++t2) {
                    const int i = m + 16 * t2;
                    const float dt = (t2 ? e1 : e0) * sc;
                    const float sn = 0.9f * soms[rr][i]
                                   + 0.1f * fmaxf(dt + somdotS[rr][i], 0.f);
                    soms[rr][i] = sn;
                    const float acc2 = (l4cur[rr][i] - dt) * (1.0f + 0.5f * dt)
                                     + l23dotS[rr][i] - 0.8f * sn - pv;
                    const float ln = 0.9f * l23s[rr][i] + 0.1f * fmaxf(acc2, 0.f);
                    l23s[rr][i] = ln;
                    out[outb + i] = ln;
                    ln01[t2] = ln;
                }
                const unsigned ph = cvtpk(ln01[0], ln01[1]);
                const unsigned pl = cvtpk(ln01[0] - lo16f(ph), ln01[1] - hi16f(ph));
                xa[0][rr][m]      = (short)ph;         xa[1][rr][m]      = (short)pl;
                xa[0][rr][m + 16] = (short)(ph >> 16); xa[1][rr][m + 16] = (short)(pl >> 16);
                if (m < 4) {
                    const int i = m + 32;
                    const float dt = e2 * sc;
                    const float sn = 0.9f * soms[rr][i]
                                   + 0.1f * fmaxf(dt + somdotS[rr][i], 0.f);
                    soms[rr][i] = sn;
                    const float acc2 = (l4cur[rr][i] - dt) * (1.0f + 0.5f * dt)
                                     + l23dotS[rr][i] - 0.8f * sn - pv;
                    const float ln = 0.9f * l23s[rr][i] + 0.1f * fmaxf(acc2, 0.f);
                    l23s[rr][i] = ln;
                    out[outb + i] = ln;
                    const short hi2 = f2bf(ln);
                    xa[0][rr][i] = hi2; xa[1][rr][i] = f2bf(ln - bf2f(hi2));
                }
            }
        } else if (isL4f) {
            // l4(t+1) = 0.9*l4(t) + 0.1*relu(l4part(t+1) - pv(t)) -> l4s[nxt]
            const float nl4 = 0.9f * l4cur[lr][li]
                            + 0.1f * fmaxf(l4part[lr][li] - pvL[lr], 0.f);
            l4nxt[lr][li] = nl4;
            const float ad = 0.98f * adL[lr][li] + 0.01f * nl4;
            adL[lr][li] = ad;
            l4part[lr][li] = stimreg - ad;     // base for t+2: stim(t+2) - adapt(t+1)
            const int tn = (t + 3 < TT) ? t + 3 : TT - 1;
            stimreg = packed[((size_t)(r0 + lr) * TT + tn) * DIN + li];
        }
        BAR();
    }
}

extern "C" void kernel_launch(void* const* d_in, const int* in_sizes, int n_in,
                              void* d_out, int out_size, void* d_ws, size_t ws_size,
                              hipStream_t stream) {
    (void)in_sizes; (void)n_in; (void)out_size; (void)ws_size;
    const float* packed = (const float*)d_in[0];
    const float* Wl4    = (const float*)d_in[1];
    const float* Wl23   = (const float*)d_in[2];
    const float* Wsom   = (const float*)d_in[3];
    const float* Wz     = (const float*)d_in[4];
    const float* Wr     = (const float*)d_in[5];
    const float* Wh     = (const float*)d_in[6];
    const float* bz     = (const float*)d_in[7];
    const float* br     = (const float*)d_in[8];
    const float* bh     = (const float*)d_in[9];
    const float* Wq     = (const float*)d_in[10];
    const float* bq     = (const float*)d_in[11];
    const float* Wp     = (const float*)d_in[12];
    const float* bp     = (const float*)d_in[13];
    float* out  = (float*)d_out;
    short* frag = (short*)d_ws;   // needs 184320 B

    init_frags<<<(FRAG_TOTAL + 255) / 256, 256, 0, stream>>>(Wz, Wr, Wh, Wq, Wp, frag);
    laminar_kernel<<<256, 1024, 0, stream>>>(packed, Wl4, Wl23, Wsom,
                                             bz, br, bh, bq, bp, frag, out);
}